// Round 7
// baseline (1131.984 us; speedup 1.0000x reference)
//
#include <hip/hip_runtime.h>

#define NN 128
#define NITER 300
#define NSTEP 12   // R5-proven: cold safeguarded Newton, bracket-clamped (absmax 2.4e-4).
                   // R6 taught: warm start + fewer steps fails on flat pieces of s(tau).

typedef float v2f __attribute__((ext_vector_type(2)));

// ---- DPP wave-64 cross-lane helpers ----
template<int CTRL>
__device__ __forceinline__ float dpp0(float x) {  // invalid lanes contribute 0
  return __int_as_float(__builtin_amdgcn_update_dpp(0, __float_as_int(x), CTRL, 0xF, 0xF, true));
}
template<int CTRL>
__device__ __forceinline__ float dppS(float x) {  // invalid lanes keep self
  int xi = __float_as_int(x);
  return __int_as_float(__builtin_amdgcn_update_dpp(xi, xi, CTRL, 0xF, 0xF, false));
}
__device__ __forceinline__ float bcast63(float x) {
  return __int_as_float(__builtin_amdgcn_readlane(__float_as_int(x), 63));
}
__device__ __forceinline__ float wsum(float x) {
  x += dpp0<0x111>(x); x += dpp0<0x112>(x); x += dpp0<0x114>(x);
  x += dpp0<0x118>(x); x += dpp0<0x142>(x); x += dpp0<0x143>(x);
  return bcast63(x);
}
__device__ __forceinline__ void wsum2(float& x, float& y) {  // two interleaved chains
  float a = x, b = y;
  a += dpp0<0x111>(a); b += dpp0<0x111>(b);
  a += dpp0<0x112>(a); b += dpp0<0x112>(b);
  a += dpp0<0x114>(a); b += dpp0<0x114>(b);
  a += dpp0<0x118>(a); b += dpp0<0x118>(b);
  a += dpp0<0x142>(a); b += dpp0<0x142>(b);
  a += dpp0<0x143>(a); b += dpp0<0x143>(b);
  x = bcast63(a); y = bcast63(b);
}
__device__ __forceinline__ void wminmax(float& mn, float& mx) {  // interleaved
  mn = fminf(mn, dppS<0x111>(mn)); mx = fmaxf(mx, dppS<0x111>(mx));
  mn = fminf(mn, dppS<0x112>(mn)); mx = fmaxf(mx, dppS<0x112>(mx));
  mn = fminf(mn, dppS<0x114>(mn)); mx = fmaxf(mx, dppS<0x114>(mx));
  mn = fminf(mn, dppS<0x118>(mn)); mx = fmaxf(mx, dppS<0x118>(mx));
  mn = fminf(mn, dppS<0x142>(mn)); mx = fmaxf(mx, dppS<0x142>(mx));
  mn = fminf(mn, dppS<0x143>(mn)); mx = fmaxf(mx, dppS<0x143>(mx));
  mn = bcast63(mn); mx = bcast63(mx);
}

// ONE WAVE PER SAMPLE (R5 structure): 1024 waves = 1 wave/SIMD device-wide.
// Q in-wave as float2 column-pairs: qA[u] = Q2[lane][{2u,2u+1}], qB = row lane+64.
// Matvec: y staged in LDS, wave-uniform ds_read_b128 broadcasts + v_pk_fma_f32.
__launch_bounds__(64, 1)
__global__ void markowitz_kernel(const float* __restrict__ rets,
                                 const float* __restrict__ cov,
                                 const float* __restrict__ gam,
                                 const float* __restrict__ alp,
                                 float* __restrict__ out)
{
  __shared__ __align__(16) float cs[16 * NN];   // 8 KB staging chunk (16 rows of C)
  __shared__ __align__(16) float yLds[NN];

  const int b    = blockIdx.x;
  const int lane = threadIdx.x;          // block = exactly one wave (64)

  const float g   = gam[b];
  const float g2  = g * g;
  const float aab = fabsf(alp[b]);
  const float* cb = cov + (size_t)b * (NN * NN);

  // ---------- build Q = g2*C^T C + aab*I, packed column pairs ----------
  v2f qA[64], qB[64];
  #pragma unroll
  for (int u = 0; u < 64; ++u) { qA[u] = (v2f)0.f; qB[u] = (v2f)0.f; }

  for (int ch = 0; ch < 8; ++ch) {       // 8 chunks x 16 rows
    const float4* src = (const float4*)(cb + (size_t)ch * 16 * NN);
    #pragma unroll
    for (int q = 0; q < 8; ++q)          // coalesced 16-row load -> LDS
      ((float4*)cs)[q * 64 + lane] = src[q * 64 + lane];
    // in-order DS per wave: reads below queue after these writes; compiler waits.
    #pragma unroll 1
    for (int kk = 0; kk < 16; ++kk) {
      float a0 = cs[kk * NN + lane];          // C[k][lane]      (stride-1, conflict-free)
      float a1 = cs[kk * NN + 64 + lane];     // C[k][lane+64]
      const float4* crow = (const float4*)(cs + kk * NN);
      #pragma unroll
      for (int j = 0; j < 32; ++j) {
        float4 c4 = crow[j];                  // wave-uniform b128 broadcast
        v2f clo; clo.x = c4.x; clo.y = c4.y;
        v2f chi; chi.x = c4.z; chi.y = c4.w;
        qA[2*j]   = __builtin_elementwise_fma((v2f)a0, clo, qA[2*j]);
        qA[2*j+1] = __builtin_elementwise_fma((v2f)a0, chi, qA[2*j+1]);
        qB[2*j]   = __builtin_elementwise_fma((v2f)a1, clo, qB[2*j]);
        qB[2*j+1] = __builtin_elementwise_fma((v2f)a1, chi, qB[2*j+1]);
      }
    }
  }

  // scale by g2, add diagonal, Frobenius^2
  v2f ssA = (v2f)0.f, ssB = (v2f)0.f;
  #pragma unroll
  for (int u = 0; u < 64; ++u) {
    v2f qa = qA[u] * g2;
    v2f qb = qB[u] * g2;
    if (2*u     == lane)      qa.x += aab;
    if (2*u + 1 == lane)      qa.y += aab;
    if (2*u     == lane + 64) qb.x += aab;
    if (2*u + 1 == lane + 64) qb.y += aab;
    qA[u] = qa; qB[u] = qb;
    ssA = __builtin_elementwise_fma(qa, qa, ssA);
    ssB = __builtin_elementwise_fma(qb, qb, ssB);
  }
  const float S    = wsum((ssA.x + ssA.y) + (ssB.x + ssB.y));
  const float step = 0.5f / sqrtf(S);    // 1/(2||Q||_F)
  const float sc   = 2.f * step;
  #pragma unroll
  for (int u = 0; u < 64; ++u) { qA[u] *= sc; qB[u] *= sc; }  // q = 2*step*Q

  const float r2a = step * rets[b * NN + lane];
  const float r2b = step * rets[b * NN + 64 + lane];

  // ---------- FISTA, fully in-wave ----------
  float y0 = 1.f / 128.f, y1 = 1.f / 128.f;   // y coords (lane, lane+64)
  float w0p = y0, w1p = y1;                   // w_prev
  float t_f = 1.f;
  yLds[lane] = y0; yLds[64 + lane] = y1;

  #pragma unroll 1
  for (int it = 0; it < NITER; ++it) {
    // matvec: 4 packed accumulator chains; y via wave-uniform b128 broadcasts
    v2f sA0 = (v2f)0.f, sA1 = (v2f)0.f, sB0 = (v2f)0.f, sB1 = (v2f)0.f;
    const float4* yp = (const float4*)yLds;
    #pragma unroll
    for (int j = 0; j < 32; ++j) {
      float4 y4 = yp[j];
      v2f ylo; ylo.x = y4.x; ylo.y = y4.y;
      v2f yhi; yhi.x = y4.z; yhi.y = y4.w;
      sA0 = __builtin_elementwise_fma(qA[2*j],   ylo, sA0);
      sA1 = __builtin_elementwise_fma(qA[2*j+1], yhi, sA1);
      sB0 = __builtin_elementwise_fma(qB[2*j],   ylo, sB0);
      sB1 = __builtin_elementwise_fma(qB[2*j+1], yhi, sB1);
    }
    float v0 = y0 - ((sA0.x + sA0.y) + (sA1.x + sA1.y)) + r2a;  // v = y - step*grad
    float v1 = y1 - ((sB0.x + sB0.y) + (sB1.x + sB1.y)) + r2b;

    // projection onto {sum w = 1, 0<=w<=1} — R5-proven form, verbatim
    float mn = fminf(v0, v1), mx = fmaxf(v0, v1);
    wminmax(mn, mx);
    float lo = mn - 1.0f, hi = mx;
    float tau = 0.5f * (lo + hi);
    #pragma unroll 1
    for (int s2 = 0; s2 < NSTEP; ++s2) {
      float z0 = v0 - tau, z1 = v1 - tau;
      float c0 = __builtin_amdgcn_fmed3f(z0, 0.f, 1.f);
      float c1 = __builtin_amdgcn_fmed3f(z1, 0.f, 1.f);
      float f0 = (c0 > 0.f && c0 < 1.f) ? 1.f : 0.f;
      float f1 = (c1 > 0.f && c1 < 1.f) ? 1.f : 0.f;
      float s = c0 + c1, nf = f0 + f1;
      wsum2(s, nf);
      bool gt = (s > 1.f);
      lo = gt ? tau : lo;
      hi = gt ? hi : tau;
      float tn = fmaf(s - 1.f, __builtin_amdgcn_rcpf(fmaxf(nf, 1.f)), tau);
      tau = (tn > lo && tn < hi) ? tn : 0.5f * (lo + hi);
    }
    float tau0 = 0.5f * (lo + hi);
    float z0 = v0 - tau0, z1 = v1 - tau0;
    bool f0 = (z0 > 0.f) && (z0 < 1.0f);
    bool f1 = (z1 > 0.f) && (z1 < 1.0f);
    bool cap0 = (z0 >= 1.0f), cap1 = (z1 >= 1.0f);
    float sfv = (f0 ? v0 : 0.f) + (f1 ? v1 : 0.f);
    float cnt = (f0 ? 1.f : 0.f) + (f1 ? 1.f : 0.f)
              + 1024.f * ((cap0 ? 1.f : 0.f) + (cap1 ? 1.f : 0.f));
    wsum2(sfv, cnt);
    float nu    = floorf(cnt * (1.f / 1024.f));
    float nfree = fmaxf(cnt - 1024.f * nu, 1.f);
    float tauf  = (sfv + nu - 1.f) / nfree;        // exact tau on fixed active set
    float w0 = f0 ? (v0 - tauf) : (cap0 ? 1.0f : 0.f);
    float w1 = f1 ? (v1 - tauf) : (cap1 ? 1.0f : 0.f);

    // FISTA momentum; publish next y to LDS (in-order DS: next iter's reads wait)
    float tn   = 0.5f * (1.f + sqrtf(1.f + 4.f * t_f * t_f));
    float coef = (t_f - 1.f) / tn;
    y0 = w0 + coef * (w0 - w0p);
    y1 = w1 + coef * (w1 - w1p);
    yLds[lane] = y0; yLds[64 + lane] = y1;
    w0p = w0; w1p = w1;
    t_f = tn;
  }

  out[(size_t)b * NN + lane]      = w0p;
  out[(size_t)b * NN + 64 + lane] = w1p;
}

extern "C" void kernel_launch(void* const* d_in, const int* in_sizes, int n_in,
                              void* d_out, int out_size, void* d_ws, size_t ws_size,
                              hipStream_t stream) {
  (void)n_in; (void)d_ws; (void)ws_size; (void)out_size;
  const float* rets = (const float*)d_in[0];
  const float* cov  = (const float*)d_in[1];
  const float* gam  = (const float*)d_in[2];
  const float* alp  = (const float*)d_in[3];
  float* out = (float*)d_out;
  const int B = in_sizes[0] / NN;   // 1024 waves, one sample each
  markowitz_kernel<<<B, 64, 0, stream>>>(rets, cov, gam, alp, out);
}

// Round 8
// 670.103 us; speedup vs baseline: 1.6893x; 1.6893x over previous
//
#include <hip/hip_runtime.h>

#define NN 128
#define NITER 300
#define NROUND 5   // 5 rounds x 4-point search: bracket /5 per round -> /3125 total
                   // (~2^11.6, same class as R5's 12 bisection halvings; R4 passed
                   // with ~1e-3 tau err). Rounds, not accuracy, were the cost.

// ---- DPP wave-64 cross-lane helpers ----
template<int CTRL>
__device__ __forceinline__ float dpp0(float x) {  // invalid lanes contribute 0
  return __int_as_float(__builtin_amdgcn_update_dpp(0, __float_as_int(x), CTRL, 0xF, 0xF, true));
}
template<int CTRL>
__device__ __forceinline__ float dppS(float x) {  // invalid lanes keep self
  int xi = __float_as_int(x);
  return __int_as_float(__builtin_amdgcn_update_dpp(xi, xi, CTRL, 0xF, 0xF, false));
}
__device__ __forceinline__ float bcast63(float x) {
  return __int_as_float(__builtin_amdgcn_readlane(__float_as_int(x), 63));
}
__device__ __forceinline__ float rlane(float x, int l) {   // l literal after unroll
  return __int_as_float(__builtin_amdgcn_readlane(__float_as_int(x), l));
}
__device__ __forceinline__ float wsum(float x) {
  x += dpp0<0x111>(x); x += dpp0<0x112>(x); x += dpp0<0x114>(x);
  x += dpp0<0x118>(x); x += dpp0<0x142>(x); x += dpp0<0x143>(x);
  return bcast63(x);
}
__device__ __forceinline__ void wsum2(float& x, float& y) {  // two interleaved chains
  float a = x, b = y;
  a += dpp0<0x111>(a); b += dpp0<0x111>(b);
  a += dpp0<0x112>(a); b += dpp0<0x112>(b);
  a += dpp0<0x114>(a); b += dpp0<0x114>(b);
  a += dpp0<0x118>(a); b += dpp0<0x118>(b);
  a += dpp0<0x142>(a); b += dpp0<0x142>(b);
  a += dpp0<0x143>(a); b += dpp0<0x143>(b);
  x = bcast63(a); y = bcast63(b);
}
__device__ __forceinline__ void wsum4(float& a, float& b, float& c, float& d) {
  // four interleaved chains: same serial-latency as one wsum, 4x the work/round
  a += dpp0<0x111>(a); b += dpp0<0x111>(b); c += dpp0<0x111>(c); d += dpp0<0x111>(d);
  a += dpp0<0x112>(a); b += dpp0<0x112>(b); c += dpp0<0x112>(c); d += dpp0<0x112>(d);
  a += dpp0<0x114>(a); b += dpp0<0x114>(b); c += dpp0<0x114>(c); d += dpp0<0x114>(d);
  a += dpp0<0x118>(a); b += dpp0<0x118>(b); c += dpp0<0x118>(c); d += dpp0<0x118>(d);
  a += dpp0<0x142>(a); b += dpp0<0x142>(b); c += dpp0<0x142>(c); d += dpp0<0x142>(d);
  a += dpp0<0x143>(a); b += dpp0<0x143>(b); c += dpp0<0x143>(c); d += dpp0<0x143>(d);
  a = bcast63(a); b = bcast63(b); c = bcast63(c); d = bcast63(d);
}
__device__ __forceinline__ void wminmax(float& mn, float& mx) {  // interleaved
  mn = fminf(mn, dppS<0x111>(mn)); mx = fmaxf(mx, dppS<0x111>(mx));
  mn = fminf(mn, dppS<0x112>(mn)); mx = fmaxf(mx, dppS<0x112>(mx));
  mn = fminf(mn, dppS<0x114>(mn)); mx = fmaxf(mx, dppS<0x114>(mx));
  mn = fminf(mn, dppS<0x118>(mn)); mx = fmaxf(mx, dppS<0x118>(mx));
  mn = fminf(mn, dppS<0x142>(mn)); mx = fmaxf(mx, dppS<0x142>(mx));
  mn = fminf(mn, dppS<0x143>(mn)); mx = fmaxf(mx, dppS<0x143>(mx));
  mn = bcast63(mn); mx = bcast63(mx);
}

// ONE WAVE PER SAMPLE (R5 structure, R5 readlane matvec — R7 proved the LDS
// path regresses at 1 wave/SIMD). Q in-wave: lane owns rows {lane, lane+64}.
__launch_bounds__(64, 1)
__global__ void markowitz_kernel(const float* __restrict__ rets,
                                 const float* __restrict__ cov,
                                 const float* __restrict__ gam,
                                 const float* __restrict__ alp,
                                 float* __restrict__ out)
{
  const int b    = blockIdx.x;
  const int lane = threadIdx.x;          // block = exactly one wave (64)

  const float g   = gam[b];
  const float g2  = g * g;
  const float aab = fabsf(alp[b]);
  const float* cb = cov + (size_t)b * (NN * NN);

  // ---------- build Q = g2*C^T C + aab*I (rows lane / lane+64) ----------
  float accA[NN], accB[NN];
  #pragma unroll
  for (int u = 0; u < NN; ++u) { accA[u] = 0.f; accB[u] = 0.f; }

  const float* ap0 = cb + lane;
  const float* ap1 = cb + lane + 64;
  #pragma unroll 2
  for (int k = 0; k < NN; ++k) {
    float a0 = ap0[(size_t)k * NN];      // C[k][lane]      (coalesced)
    float a1 = ap1[(size_t)k * NN];      // C[k][lane+64]
    #pragma unroll
    for (int u = 0; u < 64; ++u) {
      float s0 = rlane(a0, u);           // C[k][u]
      float s1 = rlane(a1, u);           // C[k][64+u]
      accA[u]      = fmaf(a0, s0, accA[u]);
      accA[64 + u] = fmaf(a0, s1, accA[64 + u]);
      accB[u]      = fmaf(a1, s0, accB[u]);
      accB[64 + u] = fmaf(a1, s1, accB[64 + u]);
    }
  }

  // scale, diagonal, Frobenius^2 (4 partial chains)
  float ss0 = 0.f, ss1 = 0.f, ss2 = 0.f, ss3 = 0.f;
  #pragma unroll
  for (int u = 0; u < NN; ++u) {
    float qa = g2 * accA[u]; if (u == lane)      qa += aab;
    float qb = g2 * accB[u]; if (u == lane + 64) qb += aab;
    accA[u] = qa; accB[u] = qb;
    if (u & 1) { ss0 = fmaf(qa, qa, ss0); ss1 = fmaf(qb, qb, ss1); }
    else       { ss2 = fmaf(qa, qa, ss2); ss3 = fmaf(qb, qb, ss3); }
  }
  const float S    = wsum((ss0 + ss2) + (ss1 + ss3));
  const float step = 0.5f / sqrtf(S);    // 1/(2||Q||_F)
  const float sc   = 2.f * step;
  #pragma unroll
  for (int u = 0; u < NN; ++u) { accA[u] *= sc; accB[u] *= sc; }  // acc = 2*step*Q

  const float r2a = step * rets[b * NN + lane];
  const float r2b = step * rets[b * NN + 64 + lane];

  // ---------- FISTA, fully in-wave ----------
  float y0 = 1.f / 128.f, y1 = 1.f / 128.f;   // y coords (lane, lane+64)
  float w0p = y0, w1p = y1;                   // w_prev
  float t_f = 1.f;

  #pragma unroll 1
  for (int it = 0; it < NITER; ++it) {
    // matvec: 4 independent fma chains, y broadcast via readlane (R5-proven)
    float pA0 = 0.f, pA1 = 0.f, pB0 = 0.f, pB1 = 0.f;
    #pragma unroll
    for (int u = 0; u < 64; ++u) {
      float t0 = rlane(y0, u);
      float t1 = rlane(y1, u);
      pA0 = fmaf(accA[u],      t0, pA0);
      pA1 = fmaf(accA[64 + u], t1, pA1);
      pB0 = fmaf(accB[u],      t0, pB0);
      pB1 = fmaf(accB[64 + u], t1, pB1);
    }
    float v0 = y0 - (pA0 + pA1) + r2a;   // v = y - step*grad
    float v1 = y1 - (pB0 + pB1) + r2b;

    // projection onto {sum w=1, 0<=w<=1}: 5 rounds x 4-point bracket search
    float mn = fminf(v0, v1), mx = fmaxf(v0, v1);
    wminmax(mn, mx);
    float lo = mn - 1.0f;
    float W  = mx - lo;
    #pragma unroll 1
    for (int r = 0; r < NROUND; ++r) {
      float h  = W * 0.2f;
      float t1v = lo + h, t2v = lo + 2.f*h, t3v = lo + 3.f*h, t4v = lo + 4.f*h;
      float s1 = __builtin_amdgcn_fmed3f(v0 - t1v, 0.f, 1.f)
               + __builtin_amdgcn_fmed3f(v1 - t1v, 0.f, 1.f);
      float s2 = __builtin_amdgcn_fmed3f(v0 - t2v, 0.f, 1.f)
               + __builtin_amdgcn_fmed3f(v1 - t2v, 0.f, 1.f);
      float s3 = __builtin_amdgcn_fmed3f(v0 - t3v, 0.f, 1.f)
               + __builtin_amdgcn_fmed3f(v1 - t3v, 0.f, 1.f);
      float s4 = __builtin_amdgcn_fmed3f(v0 - t4v, 0.f, 1.f)
               + __builtin_amdgcn_fmed3f(v1 - t4v, 0.f, 1.f);
      wsum4(s1, s2, s3, s4);
      // s monotone decreasing in tau: cnt = #points with s>1 selects sub-interval
      float cnt = ((s1 > 1.f ? 1.f : 0.f) + (s2 > 1.f ? 1.f : 0.f))
                + ((s3 > 1.f ? 1.f : 0.f) + (s4 > 1.f ? 1.f : 0.f));
      lo = fmaf(cnt, h, lo);
      W  = h;
    }
    float tau0 = lo + 0.5f * W;

    // exact tau on the (fixed) active set, then w  (R5 verbatim)
    float z0 = v0 - tau0, z1 = v1 - tau0;
    bool f0 = (z0 > 0.f) && (z0 < 1.0f);
    bool f1 = (z1 > 0.f) && (z1 < 1.0f);
    bool cap0 = (z0 >= 1.0f), cap1 = (z1 >= 1.0f);
    float sfv = (f0 ? v0 : 0.f) + (f1 ? v1 : 0.f);
    float cnt = (f0 ? 1.f : 0.f) + (f1 ? 1.f : 0.f)
              + 1024.f * ((cap0 ? 1.f : 0.f) + (cap1 ? 1.f : 0.f));
    wsum2(sfv, cnt);
    float nu    = floorf(cnt * (1.f / 1024.f));
    float nfree = fmaxf(cnt - 1024.f * nu, 1.f);
    float tauf  = (sfv + nu - 1.f) / nfree;        // exact tau on fixed active set
    float w0 = f0 ? (v0 - tauf) : (cap0 ? 1.0f : 0.f);
    float w1 = f1 ? (v1 - tauf) : (cap1 ? 1.0f : 0.f);

    // FISTA momentum
    float tn   = 0.5f * (1.f + sqrtf(1.f + 4.f * t_f * t_f));
    float coef = (t_f - 1.f) / tn;
    y0 = w0 + coef * (w0 - w0p);
    y1 = w1 + coef * (w1 - w1p);
    w0p = w0; w1p = w1;
    t_f = tn;
  }

  out[(size_t)b * NN + lane]      = w0p;
  out[(size_t)b * NN + 64 + lane] = w1p;
}

extern "C" void kernel_launch(void* const* d_in, const int* in_sizes, int n_in,
                              void* d_out, int out_size, void* d_ws, size_t ws_size,
                              hipStream_t stream) {
  (void)n_in; (void)d_ws; (void)ws_size; (void)out_size;
  const float* rets = (const float*)d_in[0];
  const float* cov  = (const float*)d_in[1];
  const float* gam  = (const float*)d_in[2];
  const float* alp  = (const float*)d_in[3];
  float* out = (float*)d_out;
  const int B = in_sizes[0] / NN;   // 1024 waves, one sample each
  markowitz_kernel<<<B, 64, 0, stream>>>(rets, cov, gam, alp, out);
}